// Round 1
// baseline (595.389 us; speedup 1.0000x reference)
//
#include <hip/hip_runtime.h>
#include <math.h>

#define B  32
#define U  4096
#define D  512     // D_DEC == D_ENC
#define H  4
#define HD 128
#define CK 31
#define CF 32
#define AU 512

// ---------------- Kernel A: phi_s, v = Wpsi @ phi_s, ck = conv (x) Wloc ----
__global__ __launch_bounds__(256) void prep_kernel(
    const float* __restrict__ dec,    // (B,512)
    const float* __restrict__ Wphi,   // (H,512,128)
    const float* __restrict__ bphi,   // (H,128)
    const float* __restrict__ Wpsi,   // (H,512,128)
    const float* __restrict__ bpsi,   // (H,128)
    const float* __restrict__ convk,  // (31,1,32)
    const float* __restrict__ Wloc,   // (32,4)
    float* __restrict__ ws_v,         // (B,H,512)
    float* __restrict__ ws_const,     // (B,H)
    float* __restrict__ ws_ck)        // (31,4)
{
    __shared__ float decs[D];
    __shared__ float phis[HD];
    const int b = blockIdx.x / H, h = blockIdx.x % H;
    const int tid = threadIdx.x;

    for (int i = tid; i < D; i += 256) decs[i] = dec[b * D + i];
    __syncthreads();

    if (tid < HD) {
        float acc = bphi[h * HD + tid];
        const float* wp = Wphi + (size_t)h * D * HD + tid;
        for (int d = 0; d < D; ++d) acc += decs[d] * wp[(size_t)d * HD];
        phis[tid] = acc;
    }
    __syncthreads();

    if (tid == 0) {
        float c = 0.f;
        for (int k = 0; k < HD; ++k) c += phis[k] * bpsi[h * HD + k];
        ws_const[b * H + h] = c;
    }

    for (int e = tid; e < D; e += 256) {
        const float* wq = Wpsi + ((size_t)h * D + e) * HD;
        float acc = 0.f;
        #pragma unroll 8
        for (int k = 0; k < HD; ++k) acc += wq[k] * phis[k];
        ws_v[((size_t)b * H + h) * D + e] = acc;
    }

    if (blockIdx.x == 0 && tid < CK * H) {
        int t = tid / H, hh = tid % H;
        float acc = 0.f;
        for (int f = 0; f < CF; ++f) acc += convk[t * CF + f] * Wloc[f * H + hh];
        ws_ck[t * H + hh] = acc;
    }
}

// ---------------- Kernel B: energy[b,h,u] = enc[b,u,:].v[b,h,:] + loc -----
__global__ __launch_bounds__(256) void energy_kernel(
    const float* __restrict__ enc,     // (B,U,512)
    const float* __restrict__ prevw,   // (B,U)
    const float* __restrict__ ws_v,    // (B,H,512)
    const float* __restrict__ ws_const,// (B,H)
    const float* __restrict__ ws_ck,   // (31,4)
    float* __restrict__ energy)        // (B,H,U)
{
    const int b    = blockIdx.y;
    const int tid  = threadIdx.x;
    const int lane = tid & 63;
    const int wave = tid >> 6;
    const int ubase = blockIdx.x * 128 + wave * 32;

    float4 v0[H], v1[H];
    #pragma unroll
    for (int h = 0; h < H; ++h) {
        const float* vp = ws_v + ((size_t)b * H + h) * D + lane * 8;
        v0[h] = *(const float4*)vp;
        v1[h] = *(const float4*)(vp + 4);
    }
    float ckr[H] = {0.f, 0.f, 0.f, 0.f};
    if (lane < CK) {
        #pragma unroll
        for (int h = 0; h < H; ++h) ckr[h] = ws_ck[lane * H + h];
    }
    const float ct = (lane < H) ? ws_const[b * H + lane] : 0.f;

    for (int r = 0; r < 32; ++r) {
        const int u = ubase + r;
        const float* erow = enc + ((size_t)b * U + u) * D + lane * 8;
        float4 e0 = *(const float4*)erow;
        float4 e1 = *(const float4*)(erow + 4);

        float pw = 0.f;
        const int up = u - 15 + lane;
        if (lane < CK && up >= 0 && up < U) pw = prevw[b * U + up];

        float p0, p1, p2, p3;
        {
            p0 = pw * ckr[0]
               + e0.x*v0[0].x + e0.y*v0[0].y + e0.z*v0[0].z + e0.w*v0[0].w
               + e1.x*v1[0].x + e1.y*v1[0].y + e1.z*v1[0].z + e1.w*v1[0].w;
            p1 = pw * ckr[1]
               + e0.x*v0[1].x + e0.y*v0[1].y + e0.z*v0[1].z + e0.w*v0[1].w
               + e1.x*v1[1].x + e1.y*v1[1].y + e1.z*v1[1].z + e1.w*v1[1].w;
            p2 = pw * ckr[2]
               + e0.x*v0[2].x + e0.y*v0[2].y + e0.z*v0[2].z + e0.w*v0[2].w
               + e1.x*v1[2].x + e1.y*v1[2].y + e1.z*v1[2].z + e1.w*v1[2].w;
            p3 = pw * ckr[3]
               + e0.x*v0[3].x + e0.y*v0[3].y + e0.z*v0[3].z + e0.w*v0[3].w
               + e1.x*v1[3].x + e1.y*v1[3].y + e1.z*v1[3].z + e1.w*v1[3].w;
        }
        #pragma unroll
        for (int s = 1; s < 64; s <<= 1) {
            p0 += __shfl_xor(p0, s);
            p1 += __shfl_xor(p1, s);
            p2 += __shfl_xor(p2, s);
            p3 += __shfl_xor(p3, s);
        }
        if (lane < H) {
            float pe = (lane == 0) ? p0 : (lane == 1) ? p1 : (lane == 2) ? p2 : p3;
            energy[((size_t)b * H + lane) * U + u] = pe + ct;
        }
    }
}

// ---------------- Kernel C: softmax over u per (b,h); mean over h ---------
__global__ __launch_bounds__(256) void softmax_kernel(
    const float* __restrict__ energy,  // (B,H,U)
    float* __restrict__ attn,          // (B,H,U)
    float* __restrict__ attw)          // (B,U) -> d_out tail
{
    __shared__ float red[4];
    const int b = blockIdx.x, tid = threadIdx.x;
    const int lane = tid & 63, wave = tid >> 6;

    float aw[16];
    #pragma unroll
    for (int i = 0; i < 16; ++i) aw[i] = 0.f;

    for (int h = 0; h < H; ++h) {
        const float* e = energy + ((size_t)b * H + h) * U;
        float p[16];
        float m = -3.402823466e38f;
        #pragma unroll
        for (int i = 0; i < 16; ++i) { p[i] = e[tid + i * 256]; m = fmaxf(m, p[i]); }
        #pragma unroll
        for (int s = 1; s < 64; s <<= 1) m = fmaxf(m, __shfl_xor(m, s));
        if (lane == 0) red[wave] = m;
        __syncthreads();
        m = fmaxf(fmaxf(red[0], red[1]), fmaxf(red[2], red[3]));
        __syncthreads();

        float sum = 0.f;
        #pragma unroll
        for (int i = 0; i < 16; ++i) { p[i] = __expf(p[i] - m); sum += p[i]; }
        #pragma unroll
        for (int s = 1; s < 64; s <<= 1) sum += __shfl_xor(sum, s);
        if (lane == 0) red[wave] = sum;
        __syncthreads();
        sum = red[0] + red[1] + red[2] + red[3];
        __syncthreads();

        const float inv = 1.0f / sum;
        float* a = attn + ((size_t)b * H + h) * U;
        #pragma unroll
        for (int i = 0; i < 16; ++i) {
            float q = p[i] * inv;
            a[tid + i * 256] = q;
            aw[i] += q;
        }
    }
    #pragma unroll
    for (int i = 0; i < 16; ++i)
        attw[(size_t)b * U + tid + i * 256] = aw[i] * 0.25f;
}

// ---------------- Kernel D: context[b,h,e] = sum_u attn * enc -------------
__global__ __launch_bounds__(256) void context_kernel(
    const float* __restrict__ enc,   // (B,U,512)
    const float* __restrict__ attn,  // (B,H,U)
    float* __restrict__ ctx)         // (B,H,512) pre-zeroed
{
    const int b  = blockIdx.y;
    const int u0 = blockIdx.x * 256;
    const int tid = threadIdx.x;

    __shared__ float a_s[H][256];
    #pragma unroll
    for (int h = 0; h < H; ++h)
        a_s[h][tid] = attn[((size_t)b * H + h) * U + u0 + tid];
    __syncthreads();

    float acc00 = 0.f, acc01 = 0.f, acc10 = 0.f, acc11 = 0.f;
    float acc20 = 0.f, acc21 = 0.f, acc30 = 0.f, acc31 = 0.f;
    const float* erow = enc + ((size_t)b * U + u0) * D;
    for (int u = 0; u < 256; ++u) {
        float e0 = erow[(size_t)u * D + tid];
        float e1 = erow[(size_t)u * D + tid + 256];
        float a0 = a_s[0][u], a1 = a_s[1][u], a2 = a_s[2][u], a3 = a_s[3][u];
        acc00 += a0 * e0; acc01 += a0 * e1;
        acc10 += a1 * e0; acc11 += a1 * e1;
        acc20 += a2 * e0; acc21 += a2 * e1;
        acc30 += a3 * e0; acc31 += a3 * e1;
    }
    atomicAdd(&ctx[((size_t)b * H + 0) * D + tid],       acc00);
    atomicAdd(&ctx[((size_t)b * H + 0) * D + tid + 256], acc01);
    atomicAdd(&ctx[((size_t)b * H + 1) * D + tid],       acc10);
    atomicAdd(&ctx[((size_t)b * H + 1) * D + tid + 256], acc11);
    atomicAdd(&ctx[((size_t)b * H + 2) * D + tid],       acc20);
    atomicAdd(&ctx[((size_t)b * H + 2) * D + tid + 256], acc21);
    atomicAdd(&ctx[((size_t)b * H + 3) * D + tid],       acc30);
    atomicAdd(&ctx[((size_t)b * H + 3) * D + tid + 256], acc31);
}

// ---------------- Kernel E: out = combined @ Wout + bout ------------------
__global__ __launch_bounds__(256) void outproj_kernel(
    const float* __restrict__ ctx,   // (B,2048) = (B,H,512) flattened
    const float* __restrict__ Wout,  // (2048,512)
    const float* __restrict__ bout,  // (512)
    float* __restrict__ outv)        // (B,512)
{
    const int b = blockIdx.y;
    const int j = blockIdx.x * 256 + threadIdx.x;
    __shared__ float c_s[H * D];
    for (int i = threadIdx.x; i < H * D; i += 256)
        c_s[i] = ctx[(size_t)b * H * D + i];
    __syncthreads();

    float acc = bout[j];
    #pragma unroll 8
    for (int i = 0; i < H * D; ++i)
        acc += c_s[i] * Wout[(size_t)i * AU + j];
    outv[(size_t)b * AU + j] = acc;
}

extern "C" void kernel_launch(void* const* d_in, const int* in_sizes, int n_in,
                              void* d_out, int out_size, void* d_ws, size_t ws_size,
                              hipStream_t stream) {
    const float* dec   = (const float*)d_in[0];
    const float* enc   = (const float*)d_in[1];
    const float* prevw = (const float*)d_in[2];
    const float* Wphi  = (const float*)d_in[3];
    const float* bphi  = (const float*)d_in[4];
    const float* Wpsi  = (const float*)d_in[5];
    const float* bpsi  = (const float*)d_in[6];
    const float* convk = (const float*)d_in[7];
    const float* Wloc  = (const float*)d_in[8];
    const float* Wout  = (const float*)d_in[9];
    const float* bout  = (const float*)d_in[10];

    float* out  = (float*)d_out;
    float* outv = out;            // (B,512) context_vector
    float* attw = out + B * AU;   // (B,U) attention_weights

    float* ws        = (float*)d_ws;
    float* ws_v      = ws;                    // 65536
    float* ws_const  = ws + 65536;            // 128
    float* ws_ck     = ws + 65664;            // 124 (pad to 65792)
    float* ws_energy = ws + 65792;            // B*H*U = 524288
    float* ws_attn   = ws_energy + B * H * U; // 524288
    float* ws_ctx    = ws_attn + B * H * U;   // 65536

    hipMemsetAsync(ws_ctx, 0, (size_t)B * H * D * sizeof(float), stream);

    prep_kernel<<<dim3(B * H), 256, 0, stream>>>(dec, Wphi, bphi, Wpsi, bpsi,
                                                 convk, Wloc, ws_v, ws_const, ws_ck);
    energy_kernel<<<dim3(U / 128, B), 256, 0, stream>>>(enc, prevw, ws_v, ws_const,
                                                        ws_ck, ws_energy);
    softmax_kernel<<<dim3(B), 256, 0, stream>>>(ws_energy, ws_attn, attw);
    context_kernel<<<dim3(U / 256, B), 256, 0, stream>>>(enc, ws_attn, ws_ctx);
    outproj_kernel<<<dim3(2, B), 256, 0, stream>>>(ws_ctx, Wout, bout, outv);
}

// Round 2
// 482.283 us; speedup vs baseline: 1.2345x; 1.2345x over previous
//
#include <hip/hip_runtime.h>
#include <math.h>

#define B  32
#define U  4096
#define D  512     // D_DEC == D_ENC
#define H  4
#define HD 128
#define CK 31
#define CF 32
#define AU 512

#define WPB    128          // wave-partials per batch row: U / 32 rows-per-wave
#define ROWS_W 32           // u-rows per wave

// ---------------- Kernel A: phi_s, v = Wpsi @ phi_s, ck = conv (x) Wloc ----
__global__ __launch_bounds__(256) void prep_kernel(
    const float* __restrict__ dec,    // (B,512)
    const float* __restrict__ Wphi,   // (H,512,128)
    const float* __restrict__ bphi,   // (H,128)
    const float* __restrict__ Wpsi,   // (H,512,128)
    const float* __restrict__ bpsi,   // (H,128)
    const float* __restrict__ convk,  // (31,1,32)
    const float* __restrict__ Wloc,   // (32,4)
    float* __restrict__ ws_v,         // (B,H,512)
    float* __restrict__ ws_const,     // (B,H)
    float* __restrict__ ws_ck)        // (31,4)
{
    __shared__ float decs[D];
    __shared__ float phis[HD];
    const int b = blockIdx.x / H, h = blockIdx.x % H;
    const int tid = threadIdx.x;

    for (int i = tid; i < D; i += 256) decs[i] = dec[b * D + i];
    __syncthreads();

    if (tid < HD) {
        float acc = bphi[h * HD + tid];
        const float* wp = Wphi + (size_t)h * D * HD + tid;
        #pragma unroll 8
        for (int d = 0; d < D; ++d) acc += decs[d] * wp[(size_t)d * HD];
        phis[tid] = acc;
    }
    __syncthreads();

    if (tid == 0) {
        float c = 0.f;
        for (int k = 0; k < HD; ++k) c += phis[k] * bpsi[h * HD + k];
        ws_const[b * H + h] = c;
    }

    for (int e = tid; e < D; e += 256) {
        const float* wq = Wpsi + ((size_t)h * D + e) * HD;
        float acc = 0.f;
        #pragma unroll 8
        for (int k = 0; k < HD; ++k) acc += wq[k] * phis[k];
        ws_v[((size_t)b * H + h) * D + e] = acc;
    }

    if (blockIdx.x == 0 && tid < CK * H) {
        int t = tid / H, hh = tid % H;
        float acc = 0.f;
        for (int f = 0; f < CF; ++f) acc += convk[t * CF + f] * Wloc[f * H + hh];
        ws_ck[t * H + hh] = acc;
    }
}

// ---- Pass 1 (fused): energy + online-softmax partial context, ONE enc read
__global__ __launch_bounds__(256) void fused_pass1(
    const float* __restrict__ enc,     // (B,U,512)
    const float* __restrict__ prevw,   // (B,U)
    const float* __restrict__ ws_v,    // (B,H,512)
    const float* __restrict__ ws_const,// (B,H)
    const float* __restrict__ ws_ck,   // (31,4)
    float* __restrict__ energy,        // (B,H,U)
    float* __restrict__ pctx,          // (B,WPB,H,512)
    float* __restrict__ pms)           // (B,WPB,H,2)  m,s
{
    const int b    = blockIdx.y;
    const int tid  = threadIdx.x;
    const int lane = tid & 63;
    const int wave = tid >> 6;
    const int widx = blockIdx.x * 4 + wave;   // 0..WPB-1
    const int ubase = widx * ROWS_W;

    // v fragments: lane owns d = lane*8 .. lane*8+7
    float4 v0[H], v1[H];
    #pragma unroll
    for (int h = 0; h < H; ++h) {
        const float* vp = ws_v + ((size_t)b * H + h) * D + lane * 8;
        v0[h] = *(const float4*)vp;
        v1[h] = *(const float4*)(vp + 4);
    }
    float ckr[H] = {0.f, 0.f, 0.f, 0.f};
    if (lane < CK) {
        #pragma unroll
        for (int h = 0; h < H; ++h) ckr[h] = ws_ck[lane * H + h];
    }
    float ct[H];
    #pragma unroll
    for (int h = 0; h < H; ++h) ct[h] = ws_const[b * H + h];

    float m0 = -3.402823466e38f, m1 = m0, m2 = m0, m3 = m0;
    float s0 = 0.f, s1 = 0.f, s2 = 0.f, s3 = 0.f;
    float4 z = {0.f, 0.f, 0.f, 0.f};
    float4 c00 = z, c01 = z, c10 = z, c11 = z, c20 = z, c21 = z, c30 = z, c31 = z;

    const bool b16 = (lane & 16) != 0;
    const bool b32 = (lane & 32) != 0;

    const float* encb = enc + ((size_t)b * U + ubase) * D + lane * 8;
    float4 e0 = *(const float4*)encb;
    float4 e1 = *(const float4*)(encb + 4);

    for (int r = 0; r < ROWS_W; ++r) {
        float4 n0, n1;
        if (r < ROWS_W - 1) {
            const float* nx = encb + (size_t)(r + 1) * D;
            n0 = *(const float4*)nx;
            n1 = *(const float4*)(nx + 4);
        }
        const int u = ubase + r;
        float pw = 0.f;
        const int up = u - 15 + lane;
        if (lane < CK && up >= 0 && up < U) pw = prevw[b * U + up];

        float p0 = pw * ckr[0]
            + e0.x*v0[0].x + e0.y*v0[0].y + e0.z*v0[0].z + e0.w*v0[0].w
            + e1.x*v1[0].x + e1.y*v1[0].y + e1.z*v1[0].z + e1.w*v1[0].w;
        float p1 = pw * ckr[1]
            + e0.x*v0[1].x + e0.y*v0[1].y + e0.z*v0[1].z + e0.w*v0[1].w
            + e1.x*v1[1].x + e1.y*v1[1].y + e1.z*v1[1].z + e1.w*v1[1].w;
        float p2 = pw * ckr[2]
            + e0.x*v0[2].x + e0.y*v0[2].y + e0.z*v0[2].z + e0.w*v0[2].w
            + e1.x*v1[2].x + e1.y*v1[2].y + e1.z*v1[2].z + e1.w*v1[2].w;
        float p3 = pw * ckr[3]
            + e0.x*v0[3].x + e0.y*v0[3].y + e0.z*v0[3].z + e0.w*v0[3].w
            + e1.x*v1[3].x + e1.y*v1[3].y + e1.z*v1[3].z + e1.w*v1[3].w;

        // ---- 9-shuffle reduce-and-broadcast of 4 values over 64 lanes ----
        // Exchange 1 (xor16): (p0,p1)->a ; (p2,p3)->bb
        float keepA = b16 ? p1 : p0, sendA = b16 ? p0 : p1;
        float a  = keepA + __shfl_xor(sendA, 16);
        float keepB = b16 ? p3 : p2, sendB = b16 ? p2 : p3;
        float bb = keepB + __shfl_xor(sendB, 16);
        // Exchange 2 (xor32): (a,bb)->c
        float keepC = b32 ? bb : a, sendC = b32 ? a : bb;
        float c = keepC + __shfl_xor(sendC, 32);
        // full reduce within 16-lane group
        c += __shfl_xor(c, 1);
        c += __shfl_xor(c, 2);
        c += __shfl_xor(c, 4);
        c += __shfl_xor(c, 8);
        // broadcast the 4 group results to all lanes
        float d1 = __shfl_xor(c, 16);
        float d2 = __shfl_xor(c, 32);
        float d3 = __shfl_xor(d1, 32);
        float eh0 = (b32 ? (b16 ? d3 : d2) : (b16 ? d1 : c)) + ct[0];
        float eh1 = (b32 ? (b16 ? d2 : d3) : (b16 ? c  : d1)) + ct[1];
        float eh2 = (b32 ? (b16 ? d1 : c ) : (b16 ? d3 : d2)) + ct[2];
        float eh3 = (b32 ? (b16 ? c  : d1) : (b16 ? d2 : d3)) + ct[3];

        if (lane < H) {
            float ev = (lane == 0) ? eh0 : (lane == 1) ? eh1 : (lane == 2) ? eh2 : eh3;
            energy[((size_t)b * H + lane) * U + u] = ev;
        }

        // ---- online softmax update (wave-uniform branches) ----
        float mn0 = fmaxf(m0, eh0), mn1 = fmaxf(m1, eh1);
        float mn2 = fmaxf(m2, eh2), mn3 = fmaxf(m3, eh3);
        if (mn0 > m0 || mn1 > m1 || mn2 > m2 || mn3 > m3) {
            float a0 = __expf(m0 - mn0), a1 = __expf(m1 - mn1);
            float a2 = __expf(m2 - mn2), a3 = __expf(m3 - mn3);
            s0 *= a0; s1 *= a1; s2 *= a2; s3 *= a3;
            c00.x*=a0; c00.y*=a0; c00.z*=a0; c00.w*=a0; c01.x*=a0; c01.y*=a0; c01.z*=a0; c01.w*=a0;
            c10.x*=a1; c10.y*=a1; c10.z*=a1; c10.w*=a1; c11.x*=a1; c11.y*=a1; c11.z*=a1; c11.w*=a1;
            c20.x*=a2; c20.y*=a2; c20.z*=a2; c20.w*=a2; c21.x*=a2; c21.y*=a2; c21.z*=a2; c21.w*=a2;
            c30.x*=a3; c30.y*=a3; c30.z*=a3; c30.w*=a3; c31.x*=a3; c31.y*=a3; c31.z*=a3; c31.w*=a3;
            m0 = mn0; m1 = mn1; m2 = mn2; m3 = mn3;
        }
        float w0 = __expf(eh0 - m0), w1 = __expf(eh1 - m1);
        float w2 = __expf(eh2 - m2), w3 = __expf(eh3 - m3);
        s0 += w0; s1 += w1; s2 += w2; s3 += w3;
        c00.x += w0*e0.x; c00.y += w0*e0.y; c00.z += w0*e0.z; c00.w += w0*e0.w;
        c01.x += w0*e1.x; c01.y += w0*e1.y; c01.z += w0*e1.z; c01.w += w0*e1.w;
        c10.x += w1*e0.x; c10.y += w1*e0.y; c10.z += w1*e0.z; c10.w += w1*e0.w;
        c11.x += w1*e1.x; c11.y += w1*e1.y; c11.z += w1*e1.z; c11.w += w1*e1.w;
        c20.x += w2*e0.x; c20.y += w2*e0.y; c20.z += w2*e0.z; c20.w += w2*e0.w;
        c21.x += w2*e1.x; c21.y += w2*e1.y; c21.z += w2*e1.z; c21.w += w2*e1.w;
        c30.x += w3*e0.x; c30.y += w3*e0.y; c30.z += w3*e0.z; c30.w += w3*e0.w;
        c31.x += w3*e1.x; c31.y += w3*e1.y; c31.z += w3*e1.z; c31.w += w3*e1.w;

        e0 = n0; e1 = n1;
    }

    // write per-wave partials
    const size_t pbase = ((size_t)(b * WPB + widx)) * H;
    float* p0p = pctx + (pbase + 0) * D + lane * 8;
    float* p1p = pctx + (pbase + 1) * D + lane * 8;
    float* p2p = pctx + (pbase + 2) * D + lane * 8;
    float* p3p = pctx + (pbase + 3) * D + lane * 8;
    *(float4*)p0p = c00; *(float4*)(p0p + 4) = c01;
    *(float4*)p1p = c10; *(float4*)(p1p + 4) = c11;
    *(float4*)p2p = c20; *(float4*)(p2p + 4) = c21;
    *(float4*)p3p = c30; *(float4*)(p3p + 4) = c31;
    if (lane == 0) {
        float* ms = pms + pbase * 2;
        ms[0] = m0; ms[1] = s0; ms[2] = m1; ms[3] = s1;
        ms[4] = m2; ms[5] = s2; ms[6] = m3; ms[7] = s3;
    }
}

// ---- Pass 2: combine per-wave partials -> ctx (B,H,512), save M,S --------
__global__ __launch_bounds__(256) void combine_kernel(
    const float* __restrict__ pctx,  // (B,WPB,H,512)
    const float* __restrict__ pms,   // (B,WPB,H,2)
    float* __restrict__ ctx,         // (B,H,512)
    float* __restrict__ MS)          // (B,H,2)
{
    const int bh = blockIdx.x;       // b*H+h
    const int b = bh >> 2, h = bh & 3;
    const int tid = threadIdx.x;
    __shared__ float alpha[WPB];
    __shared__ float red[256];

    float m_i = -3.402823466e38f, s_i = 0.f;
    if (tid < WPB) {
        const float* ms = pms + (((size_t)b * WPB + tid) * H + h) * 2;
        m_i = ms[0]; s_i = ms[1];
    }
    red[tid] = m_i; __syncthreads();
    for (int st = 128; st >= 1; st >>= 1) {
        if (tid < st) red[tid] = fmaxf(red[tid], red[tid + st]);
        __syncthreads();
    }
    const float M = red[0]; __syncthreads();

    float a = (tid < WPB) ? __expf(m_i - M) : 0.f;
    if (tid < WPB) alpha[tid] = a;
    red[tid] = s_i * a; __syncthreads();
    for (int st = 128; st >= 1; st >>= 1) {
        if (tid < st) red[tid] += red[tid + st];
        __syncthreads();
    }
    const float S = red[0];
    if (tid == 0) { MS[bh * 2] = M; MS[bh * 2 + 1] = S; }
    const float invS = 1.0f / S;

    float acc0 = 0.f, acc1 = 0.f;
    const float* base = pctx + ((size_t)b * WPB * H + h) * D;
    for (int i = 0; i < WPB; ++i) {
        float al = alpha[i];
        const float* p = base + (size_t)i * H * D;
        acc0 += al * p[tid];
        acc1 += al * p[tid + 256];
    }
    ctx[(size_t)bh * D + tid]       = acc0 * invS;
    ctx[(size_t)bh * D + tid + 256] = acc1 * invS;
}

// ---- Pass 3: attention_weights = mean_h softmax(energy) ------------------
__global__ __launch_bounds__(256) void attw_kernel(
    const float* __restrict__ energy,  // (B,H,U)
    const float* __restrict__ MS,      // (B,H,2)
    float* __restrict__ attw)          // (B,U)
{
    const int b = blockIdx.x, tid = threadIdx.x;
    float M[H], iS[H];
    #pragma unroll
    for (int h = 0; h < H; ++h) {
        M[h]  = MS[(b * H + h) * 2];
        iS[h] = 1.0f / MS[(b * H + h) * 2 + 1];
    }
    #pragma unroll
    for (int i = 0; i < 16; ++i) {
        const int u = tid + i * 256;
        float acc = 0.f;
        #pragma unroll
        for (int h = 0; h < H; ++h)
            acc += __expf(energy[((size_t)b * H + h) * U + u] - M[h]) * iS[h];
        attw[(size_t)b * U + u] = acc * 0.25f;
    }
}

// ---- Pass 4: out = combined @ Wout + bout (K-split 4x, atomics) ----------
__global__ __launch_bounds__(256) void outproj_kernel(
    const float* __restrict__ ctx,   // (B,2048)
    const float* __restrict__ Wout,  // (2048,512)
    const float* __restrict__ bout,  // (512)
    float* __restrict__ outv)        // (B,512) pre-zeroed
{
    const int b = blockIdx.y;
    const int j = blockIdx.x * 256 + threadIdx.x;
    const int i0 = blockIdx.z * 512;
    __shared__ float c_s[512];
    for (int i = threadIdx.x; i < 512; i += 256)
        c_s[i] = ctx[(size_t)b * (H * D) + i0 + i];
    __syncthreads();

    float acc = (blockIdx.z == 0) ? bout[j] : 0.f;
    #pragma unroll 8
    for (int i = 0; i < 512; ++i)
        acc += c_s[i] * Wout[(size_t)(i0 + i) * AU + j];
    atomicAdd(&outv[(size_t)b * AU + j], acc);
}

extern "C" void kernel_launch(void* const* d_in, const int* in_sizes, int n_in,
                              void* d_out, int out_size, void* d_ws, size_t ws_size,
                              hipStream_t stream) {
    const float* dec   = (const float*)d_in[0];
    const float* enc   = (const float*)d_in[1];
    const float* prevw = (const float*)d_in[2];
    const float* Wphi  = (const float*)d_in[3];
    const float* bphi  = (const float*)d_in[4];
    const float* Wpsi  = (const float*)d_in[5];
    const float* bpsi  = (const float*)d_in[6];
    const float* convk = (const float*)d_in[7];
    const float* Wloc  = (const float*)d_in[8];
    const float* Wout  = (const float*)d_in[9];
    const float* bout  = (const float*)d_in[10];

    float* out  = (float*)d_out;
    float* outv = out;            // (B,512) context_vector
    float* attw = out + B * AU;   // (B,U) attention_weights

    float* ws        = (float*)d_ws;
    float* ws_v      = ws;                        // 65536
    float* ws_const  = ws + 65536;                // 128
    float* ws_ck     = ws + 65664;                // 124 (pad to 65792)
    float* ws_energy = ws + 65792;                // B*H*U = 524288
    float* ws_pctx   = ws_energy + (size_t)B*H*U;             // B*WPB*H*512 = 8388608
    float* ws_pms    = ws_pctx + (size_t)B*WPB*H*D;           // B*WPB*H*2 = 32768
    float* ws_MS     = ws_pms + (size_t)B*WPB*H*2;            // 256
    float* ws_ctx    = ws_MS + 256;                            // B*H*512 = 65536

    hipMemsetAsync(outv, 0, (size_t)B * AU * sizeof(float), stream);

    prep_kernel<<<dim3(B * H), 256, 0, stream>>>(dec, Wphi, bphi, Wpsi, bpsi,
                                                 convk, Wloc, ws_v, ws_const, ws_ck);
    fused_pass1<<<dim3(WPB / 4, B), 256, 0, stream>>>(enc, prevw, ws_v, ws_const,
                                                      ws_ck, ws_energy, ws_pctx, ws_pms);
    combine_kernel<<<dim3(B * H), 256, 0, stream>>>(ws_pctx, ws_pms, ws_ctx, ws_MS);
    attw_kernel<<<dim3(B), 256, 0, stream>>>(ws_energy, ws_MS, attw);
    outproj_kernel<<<dim3(2, B, 4), 256, 0, stream>>>(ws_ctx, Wout, bout, outv);
}

// Round 3
// 448.315 us; speedup vs baseline: 1.3281x; 1.0758x over previous
//
#include <hip/hip_runtime.h>
#include <math.h>

#define B  32
#define U  4096
#define D  512     // D_DEC == D_ENC
#define H  4
#define HD 128
#define CK 31
#define CF 32
#define AU 512

#define BPB    32           // block-partials per batch row (U / 128 rows-per-block)
#define ROWS_W 32           // u-rows per wave

// ---------------- Kernel A: phi_s, v = Wpsi @ phi_s, ck = conv (x) Wloc ----
__global__ __launch_bounds__(256) void prep_kernel(
    const float* __restrict__ dec,    // (B,512)
    const float* __restrict__ Wphi,   // (H,512,128)
    const float* __restrict__ bphi,   // (H,128)
    const float* __restrict__ Wpsi,   // (H,512,128)
    const float* __restrict__ bpsi,   // (H,128)
    const float* __restrict__ convk,  // (31,1,32)
    const float* __restrict__ Wloc,   // (32,4)
    float* __restrict__ ws_v,         // (B,H,512)
    float* __restrict__ ws_const,     // (B,H)
    float* __restrict__ ws_ck)        // (31,4)
{
    __shared__ float decs[D];
    __shared__ float phis2[2][HD];
    __shared__ float phis[HD];
    const int b = blockIdx.x / H, h = blockIdx.x % H;
    const int tid = threadIdx.x;

    for (int i = tid; i < D; i += 256) decs[i] = dec[b * D + i];
    __syncthreads();

    // phi projection with all 256 threads: split K in half
    {
        const int k = tid & 127, half = tid >> 7;
        const int d0 = half * 256;
        float acc = 0.f;
        const float* wp = Wphi + (size_t)h * D * HD + (size_t)d0 * HD + k;
        #pragma unroll 8
        for (int d = 0; d < 256; ++d) acc += decs[d0 + d] * wp[(size_t)d * HD];
        phis2[half][k] = acc;
    }
    __syncthreads();
    if (tid < HD) phis[tid] = phis2[0][tid] + phis2[1][tid] + bphi[h * HD + tid];
    __syncthreads();

    if (tid == 0) {
        float c = 0.f;
        for (int k = 0; k < HD; ++k) c += phis[k] * bpsi[h * HD + k];
        ws_const[b * H + h] = c;
    }

    for (int e = tid; e < D; e += 256) {
        const float* wq = Wpsi + ((size_t)h * D + e) * HD;
        float acc = 0.f;
        #pragma unroll 8
        for (int k = 0; k < HD; ++k) acc += wq[k] * phis[k];
        ws_v[((size_t)b * H + h) * D + e] = acc;
    }

    if (blockIdx.x == 0 && tid < CK * H) {
        int t = tid / H, hh = tid % H;
        float acc = 0.f;
        for (int f = 0; f < CF; ++f) acc += convk[t * CF + f] * Wloc[f * H + hh];
        ws_ck[t * H + hh] = acc;
    }
}

// ---- Pass 1 (fused): energy + online-softmax partial context, ONE enc read
// Block handles 128 u-rows (4 waves x 32); waves merge partials in LDS ->
// ONE (m,s,ctx) partial per block instead of per wave.
__global__ __launch_bounds__(256) void fused_pass1(
    const float* __restrict__ enc,     // (B,U,512)
    const float* __restrict__ prevw,   // (B,U)
    const float* __restrict__ ws_v,    // (B,H,512)
    const float* __restrict__ ws_const,// (B,H)
    const float* __restrict__ ws_ck,   // (31,4)
    float* __restrict__ energy,        // (B,H,U)
    float* __restrict__ pctx,          // (B,BPB,H,512)
    float* __restrict__ pms)           // (B,BPB,H,2)  m,s
{
    const int b    = blockIdx.y;
    const int blk  = blockIdx.x;              // 0..BPB-1
    const int tid  = threadIdx.x;
    const int lane = tid & 63;
    const int wave = tid >> 6;
    const int ubase = (blk * 4 + wave) * ROWS_W;

    __shared__ float lctx[4][H][D];   // 32 KB
    __shared__ float lms[4][H][2];
    __shared__ float lalpha[H][4];

    // v fragments: lane owns d = lane*8 .. lane*8+7
    float4 v0[H], v1[H];
    #pragma unroll
    for (int h = 0; h < H; ++h) {
        const float* vp = ws_v + ((size_t)b * H + h) * D + lane * 8;
        v0[h] = *(const float4*)vp;
        v1[h] = *(const float4*)(vp + 4);
    }
    float ckr[H] = {0.f, 0.f, 0.f, 0.f};
    if (lane < CK) {
        #pragma unroll
        for (int h = 0; h < H; ++h) ckr[h] = ws_ck[lane * H + h];
    }
    float ct[H];
    #pragma unroll
    for (int h = 0; h < H; ++h) ct[h] = ws_const[b * H + h];

    float m0 = -3.402823466e38f, m1 = m0, m2 = m0, m3 = m0;
    float s0 = 0.f, s1 = 0.f, s2 = 0.f, s3 = 0.f;
    float4 z = {0.f, 0.f, 0.f, 0.f};
    float4 c00 = z, c01 = z, c10 = z, c11 = z, c20 = z, c21 = z, c30 = z, c31 = z;

    const bool b16 = (lane & 16) != 0;
    const bool b32 = (lane & 32) != 0;

    const float* encb = enc + ((size_t)b * U + ubase) * D + lane * 8;
    float4 e0 = *(const float4*)encb;
    float4 e1 = *(const float4*)(encb + 4);

    for (int r = 0; r < ROWS_W; ++r) {
        float4 n0, n1;
        if (r < ROWS_W - 1) {
            const float* nx = encb + (size_t)(r + 1) * D;
            n0 = *(const float4*)nx;
            n1 = *(const float4*)(nx + 4);
        }
        const int u = ubase + r;
        float pw = 0.f;
        const int up = u - 15 + lane;
        if (lane < CK && up >= 0 && up < U) pw = prevw[b * U + up];

        float p0 = pw * ckr[0]
            + e0.x*v0[0].x + e0.y*v0[0].y + e0.z*v0[0].z + e0.w*v0[0].w
            + e1.x*v1[0].x + e1.y*v1[0].y + e1.z*v1[0].z + e1.w*v1[0].w;
        float p1 = pw * ckr[1]
            + e0.x*v0[1].x + e0.y*v0[1].y + e0.z*v0[1].z + e0.w*v0[1].w
            + e1.x*v1[1].x + e1.y*v1[1].y + e1.z*v1[1].z + e1.w*v1[1].w;
        float p2 = pw * ckr[2]
            + e0.x*v0[2].x + e0.y*v0[2].y + e0.z*v0[2].z + e0.w*v0[2].w
            + e1.x*v1[2].x + e1.y*v1[2].y + e1.z*v1[2].z + e1.w*v1[2].w;
        float p3 = pw * ckr[3]
            + e0.x*v0[3].x + e0.y*v0[3].y + e0.z*v0[3].z + e0.w*v0[3].w
            + e1.x*v1[3].x + e1.y*v1[3].y + e1.z*v1[3].z + e1.w*v1[3].w;

        // ---- 9-shuffle reduce-and-broadcast of 4 values over 64 lanes ----
        float keepA = b16 ? p1 : p0, sendA = b16 ? p0 : p1;
        float a  = keepA + __shfl_xor(sendA, 16);
        float keepB = b16 ? p3 : p2, sendB = b16 ? p2 : p3;
        float bb = keepB + __shfl_xor(sendB, 16);
        float keepC = b32 ? bb : a, sendC = b32 ? a : bb;
        float c = keepC + __shfl_xor(sendC, 32);
        c += __shfl_xor(c, 1);
        c += __shfl_xor(c, 2);
        c += __shfl_xor(c, 4);
        c += __shfl_xor(c, 8);
        float d1 = __shfl_xor(c, 16);
        float d2 = __shfl_xor(c, 32);
        float d3 = __shfl_xor(d1, 32);
        float eh0 = (b32 ? (b16 ? d3 : d2) : (b16 ? d1 : c)) + ct[0];
        float eh1 = (b32 ? (b16 ? d2 : d3) : (b16 ? c  : d1)) + ct[1];
        float eh2 = (b32 ? (b16 ? d1 : c ) : (b16 ? d3 : d2)) + ct[2];
        float eh3 = (b32 ? (b16 ? c  : d1) : (b16 ? d2 : d3)) + ct[3];

        if (lane < H) {
            float ev = (lane == 0) ? eh0 : (lane == 1) ? eh1 : (lane == 2) ? eh2 : eh3;
            energy[((size_t)b * H + lane) * U + u] = ev;
        }

        // ---- online softmax update ----
        float mn0 = fmaxf(m0, eh0), mn1 = fmaxf(m1, eh1);
        float mn2 = fmaxf(m2, eh2), mn3 = fmaxf(m3, eh3);
        if (mn0 > m0 || mn1 > m1 || mn2 > m2 || mn3 > m3) {
            float a0 = __expf(m0 - mn0), a1 = __expf(m1 - mn1);
            float a2 = __expf(m2 - mn2), a3 = __expf(m3 - mn3);
            s0 *= a0; s1 *= a1; s2 *= a2; s3 *= a3;
            c00.x*=a0; c00.y*=a0; c00.z*=a0; c00.w*=a0; c01.x*=a0; c01.y*=a0; c01.z*=a0; c01.w*=a0;
            c10.x*=a1; c10.y*=a1; c10.z*=a1; c10.w*=a1; c11.x*=a1; c11.y*=a1; c11.z*=a1; c11.w*=a1;
            c20.x*=a2; c20.y*=a2; c20.z*=a2; c20.w*=a2; c21.x*=a2; c21.y*=a2; c21.z*=a2; c21.w*=a2;
            c30.x*=a3; c30.y*=a3; c30.z*=a3; c30.w*=a3; c31.x*=a3; c31.y*=a3; c31.z*=a3; c31.w*=a3;
            m0 = mn0; m1 = mn1; m2 = mn2; m3 = mn3;
        }
        float w0 = __expf(eh0 - m0), w1 = __expf(eh1 - m1);
        float w2 = __expf(eh2 - m2), w3 = __expf(eh3 - m3);
        s0 += w0; s1 += w1; s2 += w2; s3 += w3;
        c00.x += w0*e0.x; c00.y += w0*e0.y; c00.z += w0*e0.z; c00.w += w0*e0.w;
        c01.x += w0*e1.x; c01.y += w0*e1.y; c01.z += w0*e1.z; c01.w += w0*e1.w;
        c10.x += w1*e0.x; c10.y += w1*e0.y; c10.z += w1*e0.z; c10.w += w1*e0.w;
        c11.x += w1*e1.x; c11.y += w1*e1.y; c11.z += w1*e1.z; c11.w += w1*e1.w;
        c20.x += w2*e0.x; c20.y += w2*e0.y; c20.z += w2*e0.z; c20.w += w2*e0.w;
        c21.x += w2*e1.x; c21.y += w2*e1.y; c21.z += w2*e1.z; c21.w += w2*e1.w;
        c30.x += w3*e0.x; c30.y += w3*e0.y; c30.z += w3*e0.z; c30.w += w3*e0.w;
        c31.x += w3*e1.x; c31.y += w3*e1.y; c31.z += w3*e1.z; c31.w += w3*e1.w;

        e0 = n0; e1 = n1;
    }

    // ---- block-level merge of the 4 wave partials via LDS ----
    *(float4*)&lctx[wave][0][lane * 8]     = c00;
    *(float4*)&lctx[wave][0][lane * 8 + 4] = c01;
    *(float4*)&lctx[wave][1][lane * 8]     = c10;
    *(float4*)&lctx[wave][1][lane * 8 + 4] = c11;
    *(float4*)&lctx[wave][2][lane * 8]     = c20;
    *(float4*)&lctx[wave][2][lane * 8 + 4] = c21;
    *(float4*)&lctx[wave][3][lane * 8]     = c30;
    *(float4*)&lctx[wave][3][lane * 8 + 4] = c31;
    if (lane == 0) {
        lms[wave][0][0] = m0; lms[wave][0][1] = s0;
        lms[wave][1][0] = m1; lms[wave][1][1] = s1;
        lms[wave][2][0] = m2; lms[wave][2][1] = s2;
        lms[wave][3][0] = m3; lms[wave][3][1] = s3;
    }
    __syncthreads();

    const size_t pbase = ((size_t)(b * BPB + blk)) * H;
    if (tid < H) {
        const int h = tid;
        float M = fmaxf(fmaxf(lms[0][h][0], lms[1][h][0]),
                        fmaxf(lms[2][h][0], lms[3][h][0]));
        float S = 0.f;
        #pragma unroll
        for (int w = 0; w < 4; ++w) {
            float al = __expf(lms[w][h][0] - M);
            lalpha[h][w] = al;
            S += al * lms[w][h][1];
        }
        pms[(pbase + h) * 2]     = M;
        pms[(pbase + h) * 2 + 1] = S;
    }
    __syncthreads();

    #pragma unroll
    for (int h = 0; h < H; ++h) {
        const float a0 = lalpha[h][0], a1 = lalpha[h][1];
        const float a2 = lalpha[h][2], a3 = lalpha[h][3];
        #pragma unroll
        for (int half = 0; half < 2; ++half) {
            const int d = tid + half * 256;
            float val = a0 * lctx[0][h][d] + a1 * lctx[1][h][d]
                      + a2 * lctx[2][h][d] + a3 * lctx[3][h][d];
            pctx[(pbase + h) * D + d] = val;
        }
    }
}

// ---- Pass 2: combine per-block partials -> ctx (B,H,512), save M,S -------
__global__ __launch_bounds__(256) void combine_kernel(
    const float* __restrict__ pctx,  // (B,BPB,H,512)
    const float* __restrict__ pms,   // (B,BPB,H,2)
    float* __restrict__ ctx,         // (B,H,512)
    float* __restrict__ MS)          // (B,H,2)
{
    const int bh = blockIdx.x;       // b*H+h
    const int b = bh >> 2, h = bh & 3;
    const int tid = threadIdx.x;
    __shared__ float sm[BPB], ss[BPB], salpha[BPB];
    __shared__ float MSsh[2];

    if (tid < BPB) {
        sm[tid] = pms[(((size_t)b * BPB + tid) * H + h) * 2];
        ss[tid] = pms[(((size_t)b * BPB + tid) * H + h) * 2 + 1];
    }
    __syncthreads();
    if (tid == 0) {
        float M = -3.402823466e38f;
        for (int i = 0; i < BPB; ++i) M = fmaxf(M, sm[i]);
        float S = 0.f;
        for (int i = 0; i < BPB; ++i) {
            float al = __expf(sm[i] - M);
            salpha[i] = al;
            S += al * ss[i];
        }
        MSsh[0] = M; MSsh[1] = S;
        MS[bh * 2] = M; MS[bh * 2 + 1] = S;
    }
    __syncthreads();
    const float invS = 1.0f / MSsh[1];

    float acc0 = 0.f, acc1 = 0.f;
    const float* base = pctx + ((size_t)b * BPB * H + h) * D;
    #pragma unroll 4
    for (int i = 0; i < BPB; ++i) {
        float al = salpha[i];
        const float* p = base + (size_t)i * H * D;
        acc0 += al * p[tid];
        acc1 += al * p[tid + 256];
    }
    ctx[(size_t)bh * D + tid]       = acc0 * invS;
    ctx[(size_t)bh * D + tid + 256] = acc1 * invS;
}

// ---- Pass 3: attention_weights = mean_h softmax(energy) ------------------
__global__ __launch_bounds__(256) void attw_kernel(
    const float* __restrict__ energy,  // (B,H,U)
    const float* __restrict__ MS,      // (B,H,2)
    float* __restrict__ attw)          // (B,U)
{
    const int b = blockIdx.x, tid = threadIdx.x;
    float M[H], iS[H];
    #pragma unroll
    for (int h = 0; h < H; ++h) {
        M[h]  = MS[(b * H + h) * 2];
        iS[h] = 1.0f / MS[(b * H + h) * 2 + 1];
    }
    #pragma unroll
    for (int i = 0; i < 16; ++i) {
        const int u = tid + i * 256;
        float acc = 0.f;
        #pragma unroll
        for (int h = 0; h < H; ++h)
            acc += __expf(energy[((size_t)b * H + h) * U + u] - M[h]) * iS[h];
        attw[(size_t)b * U + u] = acc * 0.25f;
    }
}

// ---- Pass 4: out = combined @ Wout + bout (K-split 8x, atomics) ----------
__global__ __launch_bounds__(256) void outproj_kernel(
    const float* __restrict__ ctx,   // (B,2048)
    const float* __restrict__ Wout,  // (2048,512)
    const float* __restrict__ bout,  // (512)
    float* __restrict__ outv)        // (B,512) pre-zeroed
{
    const int b = blockIdx.y;
    const int j = blockIdx.x * 256 + threadIdx.x;
    const int i0 = blockIdx.z * 256;
    __shared__ float c_s[256];
    c_s[threadIdx.x] = ctx[(size_t)b * (H * D) + i0 + threadIdx.x];
    __syncthreads();

    float acc = (blockIdx.z == 0) ? bout[j] : 0.f;
    #pragma unroll 8
    for (int i = 0; i < 256; ++i)
        acc += c_s[i] * Wout[(size_t)(i0 + i) * AU + j];
    atomicAdd(&outv[(size_t)b * AU + j], acc);
}

extern "C" void kernel_launch(void* const* d_in, const int* in_sizes, int n_in,
                              void* d_out, int out_size, void* d_ws, size_t ws_size,
                              hipStream_t stream) {
    const float* dec   = (const float*)d_in[0];
    const float* enc   = (const float*)d_in[1];
    const float* prevw = (const float*)d_in[2];
    const float* Wphi  = (const float*)d_in[3];
    const float* bphi  = (const float*)d_in[4];
    const float* Wpsi  = (const float*)d_in[5];
    const float* bpsi  = (const float*)d_in[6];
    const float* convk = (const float*)d_in[7];
    const float* Wloc  = (const float*)d_in[8];
    const float* Wout  = (const float*)d_in[9];
    const float* bout  = (const float*)d_in[10];

    float* out  = (float*)d_out;
    float* outv = out;            // (B,512) context_vector
    float* attw = out + B * AU;   // (B,U) attention_weights

    float* ws        = (float*)d_ws;
    float* ws_v      = ws;                        // 65536
    float* ws_const  = ws + 65536;                // 128
    float* ws_ck     = ws + 65664;                // 124 (pad to 65792)
    float* ws_energy = ws + 65792;                // B*H*U = 524288
    float* ws_pctx   = ws_energy + (size_t)B*H*U;            // B*BPB*H*512 = 2097152
    float* ws_pms    = ws_pctx + (size_t)B*BPB*H*D;          // B*BPB*H*2 = 8192
    float* ws_MS     = ws_pms + (size_t)B*BPB*H*2;           // 256
    float* ws_ctx    = ws_MS + 256;                          // B*H*512 = 65536

    hipMemsetAsync(outv, 0, (size_t)B * AU * sizeof(float), stream);

    prep_kernel<<<dim3(B * H), 256, 0, stream>>>(dec, Wphi, bphi, Wpsi, bpsi,
                                                 convk, Wloc, ws_v, ws_const, ws_ck);
    fused_pass1<<<dim3(BPB, B), 256, 0, stream>>>(enc, prevw, ws_v, ws_const,
                                                  ws_ck, ws_energy, ws_pctx, ws_pms);
    combine_kernel<<<dim3(B * H), 256, 0, stream>>>(ws_pctx, ws_pms, ws_ctx, ws_MS);
    attw_kernel<<<dim3(B), 256, 0, stream>>>(ws_energy, ws_MS, attw);
    outproj_kernel<<<dim3(2, B, 8), 256, 0, stream>>>(ws_ctx, Wout, bout, outv);
}

// Round 4
// 437.189 us; speedup vs baseline: 1.3619x; 1.0254x over previous
//
#include <hip/hip_runtime.h>
#include <math.h>

#define B  32
#define U  4096
#define D  512     // D_DEC == D_ENC
#define H  4
#define HD 128
#define CK 31
#define CF 32
#define AU 512

#define BPB    32           // block-partials per batch row (U / 128 rows-per-block)
#define ROWS_W 32           // u-rows per wave

static __device__ __forceinline__ float readlane_f(float v, int l) {
    return __int_as_float(__builtin_amdgcn_readlane(__float_as_int(v), l));
}

// ---------------- Kernel A: phi_s, v = Wpsi @ phi_s, ck = conv (x) Wloc ----
__global__ __launch_bounds__(256) void prep_kernel(
    const float* __restrict__ dec,    // (B,512)
    const float* __restrict__ Wphi,   // (H,512,128)
    const float* __restrict__ bphi,   // (H,128)
    const float* __restrict__ Wpsi,   // (H,512,128)
    const float* __restrict__ bpsi,   // (H,128)
    const float* __restrict__ convk,  // (31,1,32)
    const float* __restrict__ Wloc,   // (32,4)
    float* __restrict__ ws_v,         // (B,H,512)
    float* __restrict__ ws_const,     // (B,H)
    float* __restrict__ ws_ck)        // (31,4)
{
    __shared__ float decs[D];
    __shared__ float phis2[2][HD];
    __shared__ float phis[HD];
    const int b = blockIdx.x / H, h = blockIdx.x % H;
    const int tid = threadIdx.x;

    for (int i = tid; i < D; i += 256) decs[i] = dec[b * D + i];
    __syncthreads();

    // phi projection with all 256 threads: split K in half
    {
        const int k = tid & 127, half = tid >> 7;
        const int d0 = half * 256;
        float acc = 0.f;
        const float* wp = Wphi + (size_t)h * D * HD + (size_t)d0 * HD + k;
        #pragma unroll 8
        for (int d = 0; d < 256; ++d) acc += decs[d0 + d] * wp[(size_t)d * HD];
        phis2[half][k] = acc;
    }
    __syncthreads();
    if (tid < HD) phis[tid] = phis2[0][tid] + phis2[1][tid] + bphi[h * HD + tid];
    __syncthreads();

    if (tid == 0) {
        float c = 0.f;
        for (int k = 0; k < HD; ++k) c += phis[k] * bpsi[h * HD + k];
        ws_const[b * H + h] = c;
    }

    for (int e = tid; e < D; e += 256) {
        const float* wq = Wpsi + ((size_t)h * D + e) * HD;
        float acc = 0.f;
        #pragma unroll 8
        for (int k = 0; k < HD; ++k) acc += wq[k] * phis[k];
        ws_v[((size_t)b * H + h) * D + e] = acc;
    }

    if (blockIdx.x == 0 && tid < CK * H) {
        int t = tid / H, hh = tid % H;
        float acc = 0.f;
        for (int f = 0; f < CF; ++f) acc += convk[t * CF + f] * Wloc[f * H + hh];
        ws_ck[t * H + hh] = acc;
    }
}

// ---- Pass 1 (fused): energy + online-softmax partial context, ONE enc read
// Block handles 128 u-rows (4 waves x 32); waves merge partials in LDS ->
// ONE (m,s,ctx) partial per block.
// __launch_bounds__(256,4): pin 4 waves/SIMD (<=128 VGPRs) so the 1-row
// prefetch + 4-wave TLP covers ~900cy HBM latency.
__global__ __launch_bounds__(256, 4) void fused_pass1(
    const float* __restrict__ enc,     // (B,U,512)
    const float* __restrict__ prevw,   // (B,U)
    const float* __restrict__ ws_v,    // (B,H,512)
    const float* __restrict__ ws_const,// (B,H)
    const float* __restrict__ ws_ck,   // (31,4)
    float* __restrict__ energy,        // (B,H,U)
    float* __restrict__ pctx,          // (B,BPB,H,512)
    float* __restrict__ pms)           // (B,BPB,H,2)  m,s
{
    const int b    = blockIdx.y;
    const int blk  = blockIdx.x;              // 0..BPB-1
    const int tid  = threadIdx.x;
    const int lane = tid & 63;
    const int wave = tid >> 6;
    const int ubase = (blk * 4 + wave) * ROWS_W;

    __shared__ float lctx[4][H][D];   // 32 KB
    __shared__ float lms[4][H][2];
    __shared__ float lalpha[H][4];

    // v fragments: lane owns d = lane*8 .. lane*8+7
    float4 v0[H], v1[H];
    #pragma unroll
    for (int h = 0; h < H; ++h) {
        const float* vp = ws_v + ((size_t)b * H + h) * D + lane * 8;
        v0[h] = *(const float4*)vp;
        v1[h] = *(const float4*)(vp + 4);
    }
    float ckr[H] = {0.f, 0.f, 0.f, 0.f};
    if (lane < CK) {
        #pragma unroll
        for (int h = 0; h < H; ++h) ckr[h] = ws_ck[lane * H + h];
    }
    float ct[H];
    #pragma unroll
    for (int h = 0; h < H; ++h) ct[h] = ws_const[b * H + h];

    // prevw window preload: row r, lane l needs prevw[ubase + r + l - 15],
    // and r + l <= 62 < 64, so one 64-lane register covers the whole strip.
    float w0;
    {
        const int gi = ubase - 15 + lane;
        w0 = (gi >= 0 && gi < U) ? prevw[b * U + gi] : 0.f;
    }

    float m0 = -3.402823466e38f, m1 = m0, m2 = m0, m3 = m0;
    float s0 = 0.f, s1 = 0.f, s2 = 0.f, s3 = 0.f;
    float4 z = {0.f, 0.f, 0.f, 0.f};
    float4 c00 = z, c01 = z, c10 = z, c11 = z, c20 = z, c21 = z, c30 = z, c31 = z;

    const bool b16 = (lane & 16) != 0;
    const bool b32 = (lane & 32) != 0;

    const float* encb = enc + ((size_t)b * U + ubase) * D + lane * 8;
    float4 e0 = *(const float4*)encb;
    float4 e1 = *(const float4*)(encb + 4);

    for (int r = 0; r < ROWS_W; ++r) {
        float4 n0, n1;
        if (r < ROWS_W - 1) {
            const float* nx = encb + (size_t)(r + 1) * D;
            n0 = *(const float4*)nx;
            n1 = *(const float4*)(nx + 4);
        }
        const int u = ubase + r;
        // conv window value via cross-lane pull (no per-row global load)
        float pw = __int_as_float(
            __builtin_amdgcn_ds_bpermute((r + lane) << 2, __float_as_int(w0)));

        float p0 = pw * ckr[0]
            + e0.x*v0[0].x + e0.y*v0[0].y + e0.z*v0[0].z + e0.w*v0[0].w
            + e1.x*v1[0].x + e1.y*v1[0].y + e1.z*v1[0].z + e1.w*v1[0].w;
        float p1 = pw * ckr[1]
            + e0.x*v0[1].x + e0.y*v0[1].y + e0.z*v0[1].z + e0.w*v0[1].w
            + e1.x*v1[1].x + e1.y*v1[1].y + e1.z*v1[1].z + e1.w*v1[1].w;
        float p2 = pw * ckr[2]
            + e0.x*v0[2].x + e0.y*v0[2].y + e0.z*v0[2].z + e0.w*v0[2].w
            + e1.x*v1[2].x + e1.y*v1[2].y + e1.z*v1[2].z + e1.w*v1[2].w;
        float p3 = pw * ckr[3]
            + e0.x*v0[3].x + e0.y*v0[3].y + e0.z*v0[3].z + e0.w*v0[3].w
            + e1.x*v1[3].x + e1.y*v1[3].y + e1.z*v1[3].z + e1.w*v1[3].w;

        // ---- pairwise exchange reduce: group g of 16 lanes ends with head g
        float keepA = b16 ? p1 : p0, sendA = b16 ? p0 : p1;
        float a  = keepA + __shfl_xor(sendA, 16);
        float keepB = b16 ? p3 : p2, sendB = b16 ? p2 : p3;
        float bb = keepB + __shfl_xor(sendB, 16);
        float keepC = b32 ? bb : a, sendC = b32 ? a : bb;
        float c = keepC + __shfl_xor(sendC, 32);
        c += __shfl_xor(c, 1);
        c += __shfl_xor(c, 2);
        c += __shfl_xor(c, 4);
        c += __shfl_xor(c, 8);
        // wave-uniform broadcast via readlane (SGPR-resident)
        float eh0 = readlane_f(c, 0)  + ct[0];
        float eh1 = readlane_f(c, 16) + ct[1];
        float eh2 = readlane_f(c, 32) + ct[2];
        float eh3 = readlane_f(c, 48) + ct[3];

        if (lane < H) {
            float ev = (lane == 0) ? eh0 : (lane == 1) ? eh1 : (lane == 2) ? eh2 : eh3;
            energy[((size_t)b * H + lane) * U + u] = ev;
        }

        // ---- online softmax update (wave-uniform branch) ----
        float mn0 = fmaxf(m0, eh0), mn1 = fmaxf(m1, eh1);
        float mn2 = fmaxf(m2, eh2), mn3 = fmaxf(m3, eh3);
        if (mn0 > m0 || mn1 > m1 || mn2 > m2 || mn3 > m3) {
            float a0 = __expf(m0 - mn0), a1 = __expf(m1 - mn1);
            float a2 = __expf(m2 - mn2), a3 = __expf(m3 - mn3);
            s0 *= a0; s1 *= a1; s2 *= a2; s3 *= a3;
            c00.x*=a0; c00.y*=a0; c00.z*=a0; c00.w*=a0; c01.x*=a0; c01.y*=a0; c01.z*=a0; c01.w*=a0;
            c10.x*=a1; c10.y*=a1; c10.z*=a1; c10.w*=a1; c11.x*=a1; c11.y*=a1; c11.z*=a1; c11.w*=a1;
            c20.x*=a2; c20.y*=a2; c20.z*=a2; c20.w*=a2; c21.x*=a2; c21.y*=a2; c21.z*=a2; c21.w*=a2;
            c30.x*=a3; c30.y*=a3; c30.z*=a3; c30.w*=a3; c31.x*=a3; c31.y*=a3; c31.z*=a3; c31.w*=a3;
            m0 = mn0; m1 = mn1; m2 = mn2; m3 = mn3;
        }
        float w0e = __expf(eh0 - m0), w1e = __expf(eh1 - m1);
        float w2e = __expf(eh2 - m2), w3e = __expf(eh3 - m3);
        s0 += w0e; s1 += w1e; s2 += w2e; s3 += w3e;
        c00.x += w0e*e0.x; c00.y += w0e*e0.y; c00.z += w0e*e0.z; c00.w += w0e*e0.w;
        c01.x += w0e*e1.x; c01.y += w0e*e1.y; c01.z += w0e*e1.z; c01.w += w0e*e1.w;
        c10.x += w1e*e0.x; c10.y += w1e*e0.y; c10.z += w1e*e0.z; c10.w += w1e*e0.w;
        c11.x += w1e*e1.x; c11.y += w1e*e1.y; c11.z += w1e*e1.z; c11.w += w1e*e1.w;
        c20.x += w2e*e0.x; c20.y += w2e*e0.y; c20.z += w2e*e0.z; c20.w += w2e*e0.w;
        c21.x += w2e*e1.x; c21.y += w2e*e1.y; c21.z += w2e*e1.z; c21.w += w2e*e1.w;
        c30.x += w3e*e0.x; c30.y += w3e*e0.y; c30.z += w3e*e0.z; c30.w += w3e*e0.w;
        c31.x += w3e*e1.x; c31.y += w3e*e1.y; c31.z += w3e*e1.z; c31.w += w3e*e1.w;

        e0 = n0; e1 = n1;
    }

    // ---- block-level merge of the 4 wave partials via LDS ----
    *(float4*)&lctx[wave][0][lane * 8]     = c00;
    *(float4*)&lctx[wave][0][lane * 8 + 4] = c01;
    *(float4*)&lctx[wave][1][lane * 8]     = c10;
    *(float4*)&lctx[wave][1][lane * 8 + 4] = c11;
    *(float4*)&lctx[wave][2][lane * 8]     = c20;
    *(float4*)&lctx[wave][2][lane * 8 + 4] = c21;
    *(float4*)&lctx[wave][3][lane * 8]     = c30;
    *(float4*)&lctx[wave][3][lane * 8 + 4] = c31;
    if (lane == 0) {
        lms[wave][0][0] = m0; lms[wave][0][1] = s0;
        lms[wave][1][0] = m1; lms[wave][1][1] = s1;
        lms[wave][2][0] = m2; lms[wave][2][1] = s2;
        lms[wave][3][0] = m3; lms[wave][3][1] = s3;
    }
    __syncthreads();

    const size_t pbase = ((size_t)(b * BPB + blk)) * H;
    if (tid < H) {
        const int h = tid;
        float M = fmaxf(fmaxf(lms[0][h][0], lms[1][h][0]),
                        fmaxf(lms[2][h][0], lms[3][h][0]));
        float S = 0.f;
        #pragma unroll
        for (int w = 0; w < 4; ++w) {
            float al = __expf(lms[w][h][0] - M);
            lalpha[h][w] = al;
            S += al * lms[w][h][1];
        }
        pms[(pbase + h) * 2]     = M;
        pms[(pbase + h) * 2 + 1] = S;
    }
    __syncthreads();

    #pragma unroll
    for (int h = 0; h < H; ++h) {
        const float a0 = lalpha[h][0], a1 = lalpha[h][1];
        const float a2 = lalpha[h][2], a3 = lalpha[h][3];
        #pragma unroll
        for (int half = 0; half < 2; ++half) {
            const int d = tid + half * 256;
            float val = a0 * lctx[0][h][d] + a1 * lctx[1][h][d]
                      + a2 * lctx[2][h][d] + a3 * lctx[3][h][d];
            pctx[(pbase + h) * D + d] = val;
        }
    }
}

// ---- Pass 2: combine per-block partials -> ctx (B,H,512), save M,S -------
__global__ __launch_bounds__(256) void combine_kernel(
    const float* __restrict__ pctx,  // (B,BPB,H,512)
    const float* __restrict__ pms,   // (B,BPB,H,2)
    float* __restrict__ ctx,         // (B,H,512)
    float* __restrict__ MS)          // (B,H,2)
{
    const int bh = blockIdx.x;       // b*H+h
    const int b = bh >> 2, h = bh & 3;
    const int tid = threadIdx.x;
    __shared__ float sm[BPB], ss[BPB], salpha[BPB];
    __shared__ float MSsh[2];

    if (tid < BPB) {
        sm[tid] = pms[(((size_t)b * BPB + tid) * H + h) * 2];
        ss[tid] = pms[(((size_t)b * BPB + tid) * H + h) * 2 + 1];
    }
    __syncthreads();
    if (tid == 0) {
        float M = -3.402823466e38f;
        for (int i = 0; i < BPB; ++i) M = fmaxf(M, sm[i]);
        float S = 0.f;
        for (int i = 0; i < BPB; ++i) {
            float al = __expf(sm[i] - M);
            salpha[i] = al;
            S += al * ss[i];
        }
        MSsh[0] = M; MSsh[1] = S;
        MS[bh * 2] = M; MS[bh * 2 + 1] = S;
    }
    __syncthreads();
    const float invS = 1.0f / MSsh[1];

    float acc0 = 0.f, acc1 = 0.f;
    const float* base = pctx + ((size_t)b * BPB * H + h) * D;
    #pragma unroll 4
    for (int i = 0; i < BPB; ++i) {
        float al = salpha[i];
        const float* p = base + (size_t)i * H * D;
        acc0 += al * p[tid];
        acc1 += al * p[tid + 256];
    }
    ctx[(size_t)bh * D + tid]       = acc0 * invS;
    ctx[(size_t)bh * D + tid + 256] = acc1 * invS;
}

// ---- Pass 3: attention_weights = mean_h softmax(energy) ------------------
__global__ __launch_bounds__(256) void attw_kernel(
    const float* __restrict__ energy,  // (B,H,U)
    const float* __restrict__ MS,      // (B,H,2)
    float* __restrict__ attw)          // (B,U)
{
    const int b = blockIdx.x, tid = threadIdx.x;
    float M[H], iS[H];
    #pragma unroll
    for (int h = 0; h < H; ++h) {
        M[h]  = MS[(b * H + h) * 2];
        iS[h] = 1.0f / MS[(b * H + h) * 2 + 1];
    }
    #pragma unroll
    for (int i = 0; i < 16; ++i) {
        const int u = tid + i * 256;
        float acc = 0.f;
        #pragma unroll
        for (int h = 0; h < H; ++h)
            acc += __expf(energy[((size_t)b * H + h) * U + u] - M[h]) * iS[h];
        attw[(size_t)b * U + u] = acc * 0.25f;
    }
}

// ---- Pass 4: out = combined @ Wout + bout (K-split 8x, atomics) ----------
__global__ __launch_bounds__(256) void outproj_kernel(
    const float* __restrict__ ctx,   // (B,2048)
    const float* __restrict__ Wout,  // (2048,512)
    const float* __restrict__ bout,  // (512)
    float* __restrict__ outv)        // (B,512) pre-zeroed
{
    const int b = blockIdx.y;
    const int j = blockIdx.x * 256 + threadIdx.x;
    const int i0 = blockIdx.z * 256;
    __shared__ float c_s[256];
    c_s[threadIdx.x] = ctx[(size_t)b * (H * D) + i0 + threadIdx.x];
    __syncthreads();

    float acc = (blockIdx.z == 0) ? bout[j] : 0.f;
    #pragma unroll 8
    for (int i = 0; i < 256; ++i)
        acc += c_s[i] * Wout[(size_t)(i0 + i) * AU + j];
    atomicAdd(&outv[(size_t)b * AU + j], acc);
}

extern "C" void kernel_launch(void* const* d_in, const int* in_sizes, int n_in,
                              void* d_out, int out_size, void* d_ws, size_t ws_size,
                              hipStream_t stream) {
    const float* dec   = (const float*)d_in[0];
    const float* enc   = (const float*)d_in[1];
    const float* prevw = (const float*)d_in[2];
    const float* Wphi  = (const float*)d_in[3];
    const float* bphi  = (const float*)d_in[4];
    const float* Wpsi  = (const float*)d_in[5];
    const float* bpsi  = (const float*)d_in[6];
    const float* convk = (const float*)d_in[7];
    const float* Wloc  = (const float*)d_in[8];
    const float* Wout  = (const float*)d_in[9];
    const float* bout  = (const float*)d_in[10];

    float* out  = (float*)d_out;
    float* outv = out;            // (B,512) context_vector
    float* attw = out + B * AU;   // (B,U) attention_weights

    float* ws        = (float*)d_ws;
    float* ws_v      = ws;                        // 65536
    float* ws_const  = ws + 65536;                // 128
    float* ws_ck     = ws + 65664;                // 124 (pad to 65792)
    float* ws_energy = ws + 65792;                // B*H*U = 524288
    float* ws_pctx   = ws_energy + (size_t)B*H*U;            // B*BPB*H*512 = 2097152
    float* ws_pms    = ws_pctx + (size_t)B*BPB*H*D;          // B*BPB*H*2 = 8192
    float* ws_MS     = ws_pms + (size_t)B*BPB*H*2;           // 256
    float* ws_ctx    = ws_MS + 256;                          // B*H*512 = 65536

    hipMemsetAsync(outv, 0, (size_t)B * AU * sizeof(float), stream);

    prep_kernel<<<dim3(B * H), 256, 0, stream>>>(dec, Wphi, bphi, Wpsi, bpsi,
                                                 convk, Wloc, ws_v, ws_const, ws_ck);
    fused_pass1<<<dim3(BPB, B), 256, 0, stream>>>(enc, prevw, ws_v, ws_const,
                                                  ws_ck, ws_energy, ws_pctx, ws_pms);
    combine_kernel<<<dim3(B * H), 256, 0, stream>>>(ws_pctx, ws_pms, ws_ctx, ws_MS);
    attw_kernel<<<dim3(B), 256, 0, stream>>>(ws_energy, ws_MS, attw);
    outproj_kernel<<<dim3(2, B, 8), 256, 0, stream>>>(ws_ctx, Wout, bout, outv);
}